// Round 7
// baseline (243.291 us; speedup 1.0000x reference)
//
#include <hip/hip_runtime.h>
#include <hip/hip_bf16.h>
#include <math.h>

#define B_   16
#define INP  32
#define OUP  64
#define HID  192
#define H_   96
#define W_   96
#define HW_  (H_*W_)   // 9216
#define TC   48
#define TR   48

__device__ __forceinline__ float relu6f(float v) { return fminf(fmaxf(v, 0.f), 6.f); }
__device__ __forceinline__ float bf2f(unsigned short u) {
    unsigned int x = ((unsigned int)u) << 16;
    return __uint_as_float(x);
}
__device__ __forceinline__ unsigned short f2bf(float f) {
    unsigned int x = __float_as_uint(f);
    unsigned int lsb = (x >> 16) & 1u;
    x += 0x7fffu + lsb;
    return (unsigned short)(x >> 16);
}

// ---------------------------------------------------------------------------
// K0: prep — fold BN1 into w1s[o][i], t1[o]; BN3 into w2t[c][o], t3[o]
// ---------------------------------------------------------------------------
__global__ __launch_bounds__(256) void k0_prep(
    const float* __restrict__ w1, const float* __restrict__ g1,
    const float* __restrict__ b1, const float* __restrict__ m1,
    const float* __restrict__ v1,
    const float* __restrict__ w2, const float* __restrict__ g3,
    const float* __restrict__ b3, const float* __restrict__ m3,
    const float* __restrict__ v3,
    float* __restrict__ w1s, float* __restrict__ t1,
    float* __restrict__ w2t, float* __restrict__ t3)
{
    const int idx = blockIdx.x*256 + threadIdx.x;
    if (idx < HID*INP) {
        int o = idx / INP;
        w1s[idx] = w1[idx] * g1[o]*rsqrtf(v1[o] + 1e-5f);
    } else if (idx < HID*INP + HID) {
        int o = idx - HID*INP;
        float sc = g1[o]*rsqrtf(v1[o] + 1e-5f);
        t1[o] = b1[o] - m1[o]*sc;
    } else if (idx < HID*INP + HID + HID*OUP) {
        int k = idx - (HID*INP + HID);
        int c = k / OUP, o = k % OUP;
        w2t[k] = w2[o*HID + c] * g3[o]*rsqrtf(v3[o] + 1e-5f);
    } else if (idx < HID*INP + HID + HID*OUP + OUP) {
        int o = idx - (HID*INP + HID + HID*OUP);
        float sc = g3[o]*rsqrtf(v3[o] + 1e-5f);
        t3[o] = b3[o] - m3[o]*sc;
    }
}

// ---------------------------------------------------------------------------
// K1: 1x1 conv (32->192) + BN1 + ReLU6 -> y (bf16) ; SE-weighted pooling.
// block = (b, pool-cell), 1024 threads = (px 0..255, q 0..3); each thread
// does 48 channels. x fetched ONCE per block (q-redundancy hits L1).
// ---------------------------------------------------------------------------
__global__ __launch_bounds__(1024) void k1_conv1(
    const float* __restrict__ x, const float* __restrict__ w1s,
    const float* __restrict__ t1, const float* __restrict__ se_w,
    unsigned short* __restrict__ y, float* __restrict__ se_part)
{
    __shared__ float red[16];
    const int tid = threadIdx.x;
    const int bx  = blockIdx.x;              // b*36 + cell
    const int b   = bx / 36, cell = bx % 36;
    const int br = cell / 6, bc = cell % 6;
    const int px  = tid & 255;
    const int q   = tid >> 8;                // wave-uniform (wave = 64 lanes)

    const int ty = px >> 4, tx = px & 15;
    const int h = br*16 + ty, w = bc*16 + tx;
    const int sp = h*W_ + w;

    float xr[INP];
    #pragma unroll
    for (int i = 0; i < INP; ++i) xr[i] = x[(size_t)(b*INP + i)*HW_ + sp];

    const int o0 = __builtin_amdgcn_readfirstlane(q * 48);  // SGPR channel base
    float tsum = 0.f;
    unsigned short* yb = y + ((size_t)b*HID + o0)*HW_ + sp;
    const float* t1g = t1 + o0;
    const float* swg = se_w + o0;
    for (int oo = 0; oo < 48; ++oo) {
        const float4* wv = (const float4*)(w1s + (size_t)(o0 + oo)*INP);
        float a0 = 0.f, a1 = 0.f, a2 = 0.f, a3 = 0.f;
        #pragma unroll
        for (int i4 = 0; i4 < 2; ++i4) {
            float4 p = wv[i4*4+0], qq = wv[i4*4+1], r = wv[i4*4+2], s = wv[i4*4+3];
            a0 += p.x *xr[i4*16+0]  + p.y *xr[i4*16+1]  + p.z *xr[i4*16+2]  + p.w *xr[i4*16+3];
            a1 += qq.x*xr[i4*16+4]  + qq.y*xr[i4*16+5]  + qq.z*xr[i4*16+6]  + qq.w*xr[i4*16+7];
            a2 += r.x *xr[i4*16+8]  + r.y *xr[i4*16+9]  + r.z *xr[i4*16+10] + r.w *xr[i4*16+11];
            a3 += s.x *xr[i4*16+12] + s.y *xr[i4*16+13] + s.z *xr[i4*16+14] + s.w *xr[i4*16+15];
        }
        float yv = relu6f((a0+a1) + (a2+a3) + t1g[oo]);
        yb[(size_t)oo*HW_] = f2bf(yv);
        tsum += swg[oo]*yv;     // pool on f32 value (matches ref)
    }

    // wave-level shuffle reduce, then 16 wave-partials via LDS
    #pragma unroll
    for (int off = 32; off > 0; off >>= 1) tsum += __shfl_down(tsum, off, 64);
    if ((tid & 63) == 0) red[tid >> 6] = tsum;
    __syncthreads();
    if (tid == 0) {
        float s = 0.f;
        #pragma unroll
        for (int i = 0; i < 16; ++i) s += red[i];
        se_part[bx] = s;
    }
}

// ---------------------------------------------------------------------------
// K2: se6[b,cell] = sigmoid(pooled/256 + se_b)
// ---------------------------------------------------------------------------
__global__ __launch_bounds__(256) void k2_se(
    const float* __restrict__ se_part, const float* __restrict__ se_b,
    float* __restrict__ se6)
{
    const int id = blockIdx.x*256 + threadIdx.x;
    if (id < B_*36) {
        float logit = se_part[id]*(1.f/256.f) + se_b[0];
        se6[id] = 1.f/(1.f + expf(-logit));
    }
}

// ---------------------------------------------------------------------------
// K3: per (b,h) row — bilinear SE upsample, cumsum xx, searchsorted ->
//     iW, AW=se0*(1-t), BW=se1*t, mm (warped se)
// ---------------------------------------------------------------------------
__global__ __launch_bounds__(128) void k3_rows(
    const float* __restrict__ se6,
    int* __restrict__ iW, float* __restrict__ AW, float* __restrict__ BW,
    float* __restrict__ mm)
{
    const int bx = blockIdx.x;            // b*H_ + h
    const int b = bx / H_, h = bx % H_;
    const int tid = threadIdx.x;
    __shared__ float ysr[W_];
    __shared__ float xxl[W_];

    const float* s6 = se6 + b*36;
    float ch = h * (5.0f/95.0f);
    int r0 = (int)floorf(ch); r0 = min(max(r0, 0), 4);
    float fr = ch - (float)r0;

    if (tid < W_) {
        float cw = tid * (5.0f/95.0f);
        int c0 = (int)floorf(cw); c0 = min(max(c0, 0), 4);
        float fc = cw - (float)c0;
        float v00 = s6[r0*6 + c0],     v01 = s6[r0*6 + c0 + 1];
        float v10 = s6[(r0+1)*6 + c0], v11 = s6[(r0+1)*6 + c0 + 1];
        float ra = v00*(1.f-fr) + v10*fr;
        float rb = v01*(1.f-fr) + v11*fr;
        ysr[tid] = ra*(1.f-fc) + rb*fc;
    }
    __syncthreads();
    if (tid == 0) {
        float rs = 0.f;
        for (int w = 0; w < W_; ++w) rs += ysr[w] + 0.001f;
        float scale = (W_*0.5f)/rs;
        float cum = 0.f;
        for (int w = 0; w < W_; ++w) { cum += scale*(ysr[w]+0.001f) + 0.5f; xxl[w] = cum; }
    }
    __syncthreads();
    if (tid < TC) {
        float cq = tid * 2.0f;
        int cnt = 0;
        for (int w = 0; w < W_; ++w) cnt += (xxl[w] < cq) ? 1 : 0;
        int i = min(max(cnt - 1, 0), W_ - 2);
        float x0 = xxl[i], x1 = xxl[i+1];
        float t = (cq - x0)/(x1 - x0);
        int idx = bx*TC + tid;
        float s0 = ysr[i], s1v = ysr[i+1];
        iW[idx] = i;
        AW[idx] = s0*(1.f - t);
        BW[idx] = s1v*t;
        mm[idx] = s0 + (s1v - s0)*t;
    }
}

// ---------------------------------------------------------------------------
// K5: per (b,j) column — cumsum yy over h, searchsorted -> i2T/A2T/B2T [b][r][j]
// ---------------------------------------------------------------------------
__global__ __launch_bounds__(128) void k5_cols(
    const float* __restrict__ mm, int* __restrict__ i2T,
    float* __restrict__ A2T, float* __restrict__ B2T)
{
    const int bx = blockIdx.x;            // b*TC + j
    const int b = bx / TC, j = bx % TC;
    const int tid = threadIdx.x;
    __shared__ float cmv[H_], yyl[H_];

    if (tid < H_) cmv[tid] = mm[(b*H_ + tid)*TC + j] + 0.001f;
    __syncthreads();
    if (tid == 0) {
        float cs = 0.f;
        for (int hh = 0; hh < H_; ++hh) cs += cmv[hh];
        float scale = (H_*0.5f)/cs;
        float cum = 0.f;
        for (int hh = 0; hh < H_; ++hh) { cum += scale*cmv[hh] + 0.5f; yyl[hh] = cum; }
    }
    __syncthreads();
    if (tid < TR) {
        float rq = tid * 2.0f;
        int cnt = 0;
        for (int hh = 0; hh < H_; ++hh) cnt += (yyl[hh] < rq) ? 1 : 0;
        int i2 = min(max(cnt - 1, 0), H_ - 2);
        float p0 = yyl[i2], p1 = yyl[i2+1];
        float t2 = (rq - p0)/(p1 - p0);
        int idx = (b*TR + tid)*TC + j;
        i2T[idx] = i2; A2T[idx] = 1.f - t2; B2T[idx] = t2;
    }
}

// ---------------------------------------------------------------------------
// K4: FUSED horizontal warp + vertical warp + depthwise 3x3 + BN2 + ReLU6.
// block = one (b,c) plane; y-plane (bf16) staged in LDS with coalesced loads;
// mf (96x48) and ff (48x48) live in LDS only.
// ---------------------------------------------------------------------------
__global__ __launch_bounds__(256) void k4_warp_dw(
    const unsigned short* __restrict__ y,
    const int* __restrict__ iW, const float* __restrict__ AW,
    const float* __restrict__ BW,
    const int* __restrict__ i2T, const float* __restrict__ A2T,
    const float* __restrict__ B2T,
    const float* __restrict__ wdw,
    const float* __restrict__ g2, const float* __restrict__ b2,
    const float* __restrict__ m2, const float* __restrict__ v2,
    float* __restrict__ z1)
{
    __shared__ unsigned short ypl[HW_];  // 18 KiB (bf16 plane)
    __shared__ float mfs[H_*TC];         // 18 KiB
    __shared__ float ffs[TR*TC];         //  9 KiB
    const int tid = threadIdx.x;
    const int b = blockIdx.x / HID;
    const int c = blockIdx.x % HID;

    const uint4* ysrc = (const uint4*)(y + (size_t)(b*HID + c)*HW_);
    uint4* ydst = (uint4*)ypl;
    for (int k = tid; k < HW_/8; k += 256) ydst[k] = ysrc[k];
    __syncthreads();

    const int rbase = b*H_*TC;
    for (int k = tid; k < H_*TC; k += 256) {
        int h = k / TC;
        int rid = rbase + k;
        int i = iW[rid];
        float y0 = bf2f(ypl[h*W_ + i]);
        float y1 = bf2f(ypl[h*W_ + i + 1]);
        mfs[k] = y0*AW[rid] + y1*BW[rid];
    }
    __syncthreads();

    const int r2base = b*TR*TC;
    for (int k = tid; k < TR*TC; k += 256) {
        int j = k % TC;
        int rid = r2base + k;
        int i2 = i2T[rid];
        ffs[k] = mfs[i2*TC + j]*A2T[rid] + mfs[(i2+1)*TC + j]*B2T[rid];
    }

    float wk[9];
    #pragma unroll
    for (int k = 0; k < 9; ++k) wk[k] = wdw[c*9 + k];
    float sc = g2[c]*rsqrtf(v2[c] + 1e-5f);
    float sh = b2[c] - m2[c]*sc;
    __syncthreads();

    float* zp = z1 + (size_t)(b*HID + c)*TR*TC;
    for (int k = tid; k < TR*TC; k += 256) {
        int r = k / TC, j = k % TC;
        float acc = 0.f;
        #pragma unroll
        for (int dr = -1; dr <= 1; ++dr)
            #pragma unroll
            for (int dj = -1; dj <= 1; ++dj) {
                int rr = r + dr, jj = j + dj;
                if (rr >= 0 && rr < TR && jj >= 0 && jj < TC)
                    acc += ffs[rr*TC + jj]*wk[(dr+1)*3 + (dj+1)];
            }
        zp[k] = relu6f(acc*sc + sh);
    }
}

// ---------------------------------------------------------------------------
// K8: 1x1 conv (192->64) + BN3 -> out. Register-tiled:
// thread = 4 px (float4) x 4 outputs; block = 16 pxg (64 px) x 16 o-chunks.
// ---------------------------------------------------------------------------
__global__ __launch_bounds__(256) void k8_conv2(
    const float* __restrict__ z1, const float* __restrict__ w2t,
    const float* __restrict__ t3, float* __restrict__ out)
{
    const int tid = threadIdx.x;
    const int pxg = tid & 15;
    const int oc  = tid >> 4;
    const int pix0 = blockIdx.x*64 + pxg*4;
    const int b   = pix0 / (TR*TC);
    const int sp  = pix0 % (TR*TC);

    float acc[4][4];
    #pragma unroll
    for (int p = 0; p < 4; ++p)
        #pragma unroll
        for (int o = 0; o < 4; ++o) acc[p][o] = 0.f;

    const float* zb = z1 + (size_t)b*HID*TR*TC + sp;
    const float* wb = w2t + oc*4;
    #pragma unroll 4
    for (int c = 0; c < HID; ++c) {
        float4 z = *(const float4*)(zb + (size_t)c*TR*TC);
        float4 w = *(const float4*)(wb + c*OUP);
        acc[0][0] += z.x*w.x; acc[0][1] += z.x*w.y; acc[0][2] += z.x*w.z; acc[0][3] += z.x*w.w;
        acc[1][0] += z.y*w.x; acc[1][1] += z.y*w.y; acc[1][2] += z.y*w.z; acc[1][3] += z.y*w.w;
        acc[2][0] += z.z*w.x; acc[2][1] += z.z*w.y; acc[2][2] += z.z*w.z; acc[2][3] += z.z*w.w;
        acc[3][0] += z.w*w.x; acc[3][1] += z.w*w.y; acc[3][2] += z.w*w.z; acc[3][3] += z.w*w.w;
    }

    const float4 tt = *(const float4*)(t3 + oc*4);
    float* ob = out + (size_t)b*OUP*TR*TC + sp;
    #pragma unroll
    for (int o = 0; o < 4; ++o) {
        float tb = (o==0)?tt.x:(o==1)?tt.y:(o==2)?tt.z:tt.w;
        float4 r = make_float4(acc[0][o]+tb, acc[1][o]+tb, acc[2][o]+tb, acc[3][o]+tb);
        *(float4*)(ob + (size_t)(oc*4 + o)*TR*TC) = r;
    }
}

// ---------------------------------------------------------------------------
extern "C" void kernel_launch(void* const* d_in, const int* in_sizes, int n_in,
                              void* d_out, int out_size, void* d_ws, size_t ws_size,
                              hipStream_t stream)
{
    const float* x    = (const float*)d_in[0];
    const float* w1   = (const float*)d_in[1];
    const float* g1   = (const float*)d_in[2];
    const float* b1   = (const float*)d_in[3];
    const float* m1   = (const float*)d_in[4];
    const float* v1   = (const float*)d_in[5];
    const float* se_w = (const float*)d_in[6];
    const float* se_b = (const float*)d_in[7];
    const float* wdw  = (const float*)d_in[8];
    const float* g2   = (const float*)d_in[9];
    const float* b2   = (const float*)d_in[10];
    const float* m2   = (const float*)d_in[11];
    const float* v2   = (const float*)d_in[12];
    const float* w2   = (const float*)d_in[13];
    const float* g3   = (const float*)d_in[14];
    const float* b3   = (const float*)d_in[15];
    const float* m3   = (const float*)d_in[16];
    const float* v3   = (const float*)d_in[17];
    float* out = (float*)d_out;

    float* ws = (float*)d_ws;
    unsigned short* y = (unsigned short*)ws;   // 28,311,552 bf16 = 14,155,776 f
    float* z1      = ws + 14155776;            //  7,077,888
    float* se6     = ws + 21233664;            //        576
    int*   iW      = (int*)(ws + 21234240);    //     73,728
    float* AW      = ws + 21307968;            //     73,728
    float* BW      = ws + 21381696;            //     73,728
    float* mm      = ws + 21455424;            //     73,728
    int*   i2T     = (int*)(ws + 21529152);    //     36,864
    float* A2T     = ws + 21566016;            //     36,864
    float* B2T     = ws + 21602880;            //     36,864
    float* se_part = ws + 21639744;            //        576
    float* w1s     = ws + 21642048;            //      6,144
    float* t1      = ws + 21648192;            //        192
    float* w2t     = ws + 21648384;            //     12,288
    float* t3      = ws + 21660672;            //         64

    k0_prep<<<73, 256, 0, stream>>>(w1, g1, b1, m1, v1, w2, g3, b3, m3, v3,
                                    w1s, t1, w2t, t3);
    k1_conv1<<<B_*36, 1024, 0, stream>>>(x, w1s, t1, se_w, y, se_part);
    k2_se<<<3, 256, 0, stream>>>(se_part, se_b, se6);
    k3_rows<<<B_*H_, 128, 0, stream>>>(se6, iW, AW, BW, mm);
    k5_cols<<<B_*TC, 128, 0, stream>>>(mm, i2T, A2T, B2T);
    k4_warp_dw<<<B_*HID, 256, 0, stream>>>(y, iW, AW, BW, i2T, A2T, B2T,
                                           wdw, g2, b2, m2, v2, z1);
    k8_conv2<<<(B_*TR*TC)/64, 256, 0, stream>>>(z1, w2t, t3, out);
}

// Round 8
// 215.463 us; speedup vs baseline: 1.1292x; 1.1292x over previous
//
#include <hip/hip_runtime.h>
#include <hip/hip_bf16.h>
#include <math.h>

#define B_   16
#define INP  32
#define OUP  64
#define HID  192
#define H_   96
#define W_   96
#define HW_  (H_*W_)   // 9216
#define TC   48
#define TR   48

typedef __attribute__((ext_vector_type(8))) short  bf16x8;
typedef __attribute__((ext_vector_type(4))) float  f32x4;

__device__ __forceinline__ float relu6f(float v) { return fminf(fmaxf(v, 0.f), 6.f); }
__device__ __forceinline__ float bf2f(unsigned short u) {
    unsigned int x = ((unsigned int)u) << 16;
    return __uint_as_float(x);
}
__device__ __forceinline__ unsigned short f2bf(float f) {
    unsigned int x = __float_as_uint(f);
    unsigned int lsb = (x >> 16) & 1u;
    x += 0x7fffu + lsb;
    return (unsigned short)(x >> 16);
}

// ---------------------------------------------------------------------------
// K0: prep — BN1-folded bf16 weights w1b[o][i], t1[o]; BN3-folded w2t[c][o],
// t3[o]; zero se_part (ws is poisoned 0xAA before every launch).
// ---------------------------------------------------------------------------
__global__ __launch_bounds__(256) void k0_prep(
    const float* __restrict__ w1, const float* __restrict__ g1,
    const float* __restrict__ b1, const float* __restrict__ m1,
    const float* __restrict__ v1,
    const float* __restrict__ w2, const float* __restrict__ g3,
    const float* __restrict__ b3, const float* __restrict__ m3,
    const float* __restrict__ v3,
    unsigned short* __restrict__ w1b, float* __restrict__ t1,
    float* __restrict__ w2t, float* __restrict__ t3,
    float* __restrict__ se_part)
{
    const int idx = blockIdx.x*256 + threadIdx.x;
    if (idx < HID*INP) {                                    // w1b (bf16)
        int o = idx / INP;
        w1b[idx] = f2bf(w1[idx] * g1[o]*rsqrtf(v1[o] + 1e-5f));
    } else if (idx < HID*INP + HID) {                       // t1
        int o = idx - HID*INP;
        float sc = g1[o]*rsqrtf(v1[o] + 1e-5f);
        t1[o] = b1[o] - m1[o]*sc;
    } else if (idx < HID*INP + HID + HID*OUP) {             // w2t
        int k = idx - (HID*INP + HID);
        int c = k / OUP, o = k % OUP;
        w2t[k] = w2[o*HID + c] * g3[o]*rsqrtf(v3[o] + 1e-5f);
    } else if (idx < HID*INP + HID + HID*OUP + OUP) {       // t3
        int o = idx - (HID*INP + HID + HID*OUP);
        float sc = g3[o]*rsqrtf(v3[o] + 1e-5f);
        t3[o] = b3[o] - m3[o]*sc;
    } else if (idx < HID*INP + HID + HID*OUP + OUP + B_*36) { // zero se_part
        se_part[idx - (HID*INP + HID + HID*OUP + OUP)] = 0.f;
    }
}

// ---------------------------------------------------------------------------
// K1 (MFMA): 1x1 conv (32->192) + BN1 + ReLU6 -> y (bf16); SE-weighted pool.
// block = 64 px of one batch (4 waves x 16 px); each wave: 1 B-frag (x^T),
// 12 x {A-frag(w), mfma 16x16x32_bf16, epilogue}. Pool on f32 accumulators,
// wave shfl-reduce, one atomicAdd per 16-px strip (strip = single pool cell).
// ---------------------------------------------------------------------------
__global__ __launch_bounds__(256) void k1_mfma(
    const float* __restrict__ x, const unsigned short* __restrict__ w1b,
    const float* __restrict__ t1, const float* __restrict__ se_w,
    unsigned short* __restrict__ y, float* __restrict__ se_part)
{
    __shared__ unsigned short wl[HID*INP];   // 12 KiB  [oc][k] bf16
    __shared__ unsigned short xT[64*INP];    //  4 KiB  [px][k] bf16
    __shared__ float t1l[HID], sewl[HID];    //  1.5 KiB
    const int tid = threadIdx.x;
    const int bid = blockIdx.x;              // b*144 + strip64
    const int b   = bid / 144;
    const int inpx0 = (bid % 144) * 64;      // px offset within batch plane

    // stage w (bf16, straight copy, 768 x uint4)
    {
        const uint4* src = (const uint4*)w1b;
        uint4* dst = (uint4*)wl;
        dst[tid] = src[tid];
        if (tid < 256) { dst[tid+256] = src[tid+256]; dst[tid+512] = src[tid+512]; }
    }
    // stage t1 / se_w
    if (tid < HID) { t1l[tid] = t1[tid]; sewl[tid] = se_w[tid]; }
    // stage x -> xT[px][ch] bf16 (coalesced f32 reads, scattered u16 LDS writes)
    {
        const int ch = tid >> 3, q8 = tid & 7;           // 32 ch x 8 px-octets
        const float* xp = x + (size_t)(b*INP + ch)*HW_ + inpx0 + q8*8;
        float4 v0 = *(const float4*)(xp);
        float4 v1 = *(const float4*)(xp + 4);
        int p0 = q8*8;
        xT[(p0+0)*INP + ch] = f2bf(v0.x);
        xT[(p0+1)*INP + ch] = f2bf(v0.y);
        xT[(p0+2)*INP + ch] = f2bf(v0.z);
        xT[(p0+3)*INP + ch] = f2bf(v0.w);
        xT[(p0+4)*INP + ch] = f2bf(v1.x);
        xT[(p0+5)*INP + ch] = f2bf(v1.y);
        xT[(p0+6)*INP + ch] = f2bf(v1.z);
        xT[(p0+7)*INP + ch] = f2bf(v1.w);
    }
    __syncthreads();

    const int w = tid >> 6;                  // wave id 0..3 -> 16-px strip
    const int l = tid & 63;
    const int pxl = l & 15;                  // D col = B col = px
    const int kb  = l >> 4;                  // k-block (8 contiguous k)

    // B fragment: x^T[strip px][k]
    const bf16x8 bfrag = *(const bf16x8*)&xT[(w*16 + pxl)*INP + kb*8];

    const size_t ybase = (size_t)b*HID*HW_ + inpx0 + w*16 + pxl;
    float psum = 0.f;

    #pragma unroll
    for (int T = 0; T < 12; ++T) {
        const bf16x8 afrag = *(const bf16x8*)&wl[(T*16 + pxl)*INP + kb*8]; // row oc = l&15
        f32x4 acc = __builtin_amdgcn_mfma_f32_16x16x32_bf16(
                        afrag, bfrag, (f32x4){0.f,0.f,0.f,0.f}, 0, 0, 0);
        const int oc0 = T*16 + kb*4;         // D row = (lane>>4)*4 + reg
        const float4 t1v = *(const float4*)&t1l[oc0];
        const float4 swv = *(const float4*)&sewl[oc0];
        float yv0 = relu6f(acc[0] + t1v.x);
        float yv1 = relu6f(acc[1] + t1v.y);
        float yv2 = relu6f(acc[2] + t1v.z);
        float yv3 = relu6f(acc[3] + t1v.w);
        psum += swv.x*yv0 + swv.y*yv1 + swv.z*yv2 + swv.w*yv3;
        y[ybase + (size_t)(oc0+0)*HW_] = f2bf(yv0);
        y[ybase + (size_t)(oc0+1)*HW_] = f2bf(yv1);
        y[ybase + (size_t)(oc0+2)*HW_] = f2bf(yv2);
        y[ybase + (size_t)(oc0+3)*HW_] = f2bf(yv3);
    }

    // wave reduce + one atomic per strip (strip lies in exactly one pool cell)
    #pragma unroll
    for (int off = 32; off > 0; off >>= 1) psum += __shfl_down(psum, off, 64);
    if (l == 0) {
        const int spx = inpx0 + w*16;
        const int h = spx / W_, w0 = spx % W_;
        const int cell = (h >> 4)*6 + (w0 >> 4);
        atomicAdd(&se_part[b*36 + cell], psum);
    }
}

// ---------------------------------------------------------------------------
// K2: se6[b,cell] = sigmoid(pooled/256 + se_b)
// ---------------------------------------------------------------------------
__global__ __launch_bounds__(256) void k2_se(
    const float* __restrict__ se_part, const float* __restrict__ se_b,
    float* __restrict__ se6)
{
    const int id = blockIdx.x*256 + threadIdx.x;
    if (id < B_*36) {
        float logit = se_part[id]*(1.f/256.f) + se_b[0];
        se6[id] = 1.f/(1.f + expf(-logit));
    }
}

// ---------------------------------------------------------------------------
// K3: per (b,h) row — bilinear SE upsample, cumsum xx, searchsorted ->
//     iW, AW=se0*(1-t), BW=se1*t, mm (warped se)
// ---------------------------------------------------------------------------
__global__ __launch_bounds__(128) void k3_rows(
    const float* __restrict__ se6,
    int* __restrict__ iW, float* __restrict__ AW, float* __restrict__ BW,
    float* __restrict__ mm)
{
    const int bx = blockIdx.x;            // b*H_ + h
    const int b = bx / H_, h = bx % H_;
    const int tid = threadIdx.x;
    __shared__ float ysr[W_];
    __shared__ float xxl[W_];

    const float* s6 = se6 + b*36;
    float ch = h * (5.0f/95.0f);
    int r0 = (int)floorf(ch); r0 = min(max(r0, 0), 4);
    float fr = ch - (float)r0;

    if (tid < W_) {
        float cw = tid * (5.0f/95.0f);
        int c0 = (int)floorf(cw); c0 = min(max(c0, 0), 4);
        float fc = cw - (float)c0;
        float v00 = s6[r0*6 + c0],     v01 = s6[r0*6 + c0 + 1];
        float v10 = s6[(r0+1)*6 + c0], v11 = s6[(r0+1)*6 + c0 + 1];
        float ra = v00*(1.f-fr) + v10*fr;
        float rb = v01*(1.f-fr) + v11*fr;
        ysr[tid] = ra*(1.f-fc) + rb*fc;
    }
    __syncthreads();
    if (tid == 0) {
        float rs = 0.f;
        for (int w = 0; w < W_; ++w) rs += ysr[w] + 0.001f;
        float scale = (W_*0.5f)/rs;
        float cum = 0.f;
        for (int w = 0; w < W_; ++w) { cum += scale*(ysr[w]+0.001f) + 0.5f; xxl[w] = cum; }
    }
    __syncthreads();
    if (tid < TC) {
        float cq = tid * 2.0f;
        int cnt = 0;
        for (int w = 0; w < W_; ++w) cnt += (xxl[w] < cq) ? 1 : 0;
        int i = min(max(cnt - 1, 0), W_ - 2);
        float x0 = xxl[i], x1 = xxl[i+1];
        float t = (cq - x0)/(x1 - x0);
        int idx = bx*TC + tid;
        float s0 = ysr[i], s1v = ysr[i+1];
        iW[idx] = i;
        AW[idx] = s0*(1.f - t);
        BW[idx] = s1v*t;
        mm[idx] = s0 + (s1v - s0)*t;
    }
}

// ---------------------------------------------------------------------------
// K5: per (b,j) column — cumsum yy over h, searchsorted -> i2T/A2T/B2T [b][r][j]
// ---------------------------------------------------------------------------
__global__ __launch_bounds__(128) void k5_cols(
    const float* __restrict__ mm, int* __restrict__ i2T,
    float* __restrict__ A2T, float* __restrict__ B2T)
{
    const int bx = blockIdx.x;            // b*TC + j
    const int b = bx / TC, j = bx % TC;
    const int tid = threadIdx.x;
    __shared__ float cmv[H_], yyl[H_];

    if (tid < H_) cmv[tid] = mm[(b*H_ + tid)*TC + j] + 0.001f;
    __syncthreads();
    if (tid == 0) {
        float cs = 0.f;
        for (int hh = 0; hh < H_; ++hh) cs += cmv[hh];
        float scale = (H_*0.5f)/cs;
        float cum = 0.f;
        for (int hh = 0; hh < H_; ++hh) { cum += scale*cmv[hh] + 0.5f; yyl[hh] = cum; }
    }
    __syncthreads();
    if (tid < TR) {
        float rq = tid * 2.0f;
        int cnt = 0;
        for (int hh = 0; hh < H_; ++hh) cnt += (yyl[hh] < rq) ? 1 : 0;
        int i2 = min(max(cnt - 1, 0), H_ - 2);
        float p0 = yyl[i2], p1 = yyl[i2+1];
        float t2 = (rq - p0)/(p1 - p0);
        int idx = (b*TR + tid)*TC + j;
        i2T[idx] = i2; A2T[idx] = 1.f - t2; B2T[idx] = t2;
    }
}

// ---------------------------------------------------------------------------
// K4: FUSED horizontal warp + vertical warp + depthwise 3x3 + BN2 + ReLU6.
// block = one (b,c) plane; y-plane (bf16) staged in LDS with coalesced loads;
// mf (96x48) and ff (48x48) live in LDS only.
// ---------------------------------------------------------------------------
__global__ __launch_bounds__(256) void k4_warp_dw(
    const unsigned short* __restrict__ y,
    const int* __restrict__ iW, const float* __restrict__ AW,
    const float* __restrict__ BW,
    const int* __restrict__ i2T, const float* __restrict__ A2T,
    const float* __restrict__ B2T,
    const float* __restrict__ wdw,
    const float* __restrict__ g2, const float* __restrict__ b2,
    const float* __restrict__ m2, const float* __restrict__ v2,
    float* __restrict__ z1)
{
    __shared__ unsigned short ypl[HW_];  // 18 KiB (bf16 plane)
    __shared__ float mfs[H_*TC];         // 18 KiB
    __shared__ float ffs[TR*TC];         //  9 KiB
    const int tid = threadIdx.x;
    const int b = blockIdx.x / HID;
    const int c = blockIdx.x % HID;

    const uint4* ysrc = (const uint4*)(y + (size_t)(b*HID + c)*HW_);
    uint4* ydst = (uint4*)ypl;
    for (int k = tid; k < HW_/8; k += 256) ydst[k] = ysrc[k];
    __syncthreads();

    const int rbase = b*H_*TC;
    for (int k = tid; k < H_*TC; k += 256) {
        int h = k / TC;
        int rid = rbase + k;
        int i = iW[rid];
        float y0 = bf2f(ypl[h*W_ + i]);
        float y1 = bf2f(ypl[h*W_ + i + 1]);
        mfs[k] = y0*AW[rid] + y1*BW[rid];
    }
    __syncthreads();

    const int r2base = b*TR*TC;
    for (int k = tid; k < TR*TC; k += 256) {
        int j = k % TC;
        int rid = r2base + k;
        int i2 = i2T[rid];
        ffs[k] = mfs[i2*TC + j]*A2T[rid] + mfs[(i2+1)*TC + j]*B2T[rid];
    }

    float wk[9];
    #pragma unroll
    for (int k = 0; k < 9; ++k) wk[k] = wdw[c*9 + k];
    float sc = g2[c]*rsqrtf(v2[c] + 1e-5f);
    float sh = b2[c] - m2[c]*sc;
    __syncthreads();

    float* zp = z1 + (size_t)(b*HID + c)*TR*TC;
    for (int k = tid; k < TR*TC; k += 256) {
        int r = k / TC, j = k % TC;
        float acc = 0.f;
        #pragma unroll
        for (int dr = -1; dr <= 1; ++dr)
            #pragma unroll
            for (int dj = -1; dj <= 1; ++dj) {
                int rr = r + dr, jj = j + dj;
                if (rr >= 0 && rr < TR && jj >= 0 && jj < TC)
                    acc += ffs[rr*TC + jj]*wk[(dr+1)*3 + (dj+1)];
            }
        zp[k] = relu6f(acc*sc + sh);
    }
}

// ---------------------------------------------------------------------------
// K8: 1x1 conv (192->64) + BN3 -> out. Register-tiled:
// thread = 4 px (float4) x 4 outputs; block = 16 pxg (64 px) x 16 o-chunks.
// ---------------------------------------------------------------------------
__global__ __launch_bounds__(256) void k8_conv2(
    const float* __restrict__ z1, const float* __restrict__ w2t,
    const float* __restrict__ t3, float* __restrict__ out)
{
    const int tid = threadIdx.x;
    const int pxg = tid & 15;
    const int oc  = tid >> 4;
    const int pix0 = blockIdx.x*64 + pxg*4;
    const int b   = pix0 / (TR*TC);
    const int sp  = pix0 % (TR*TC);

    float acc[4][4];
    #pragma unroll
    for (int p = 0; p < 4; ++p)
        #pragma unroll
        for (int o = 0; o < 4; ++o) acc[p][o] = 0.f;

    const float* zb = z1 + (size_t)b*HID*TR*TC + sp;
    const float* wb = w2t + oc*4;
    #pragma unroll 4
    for (int c = 0; c < HID; ++c) {
        float4 z = *(const float4*)(zb + (size_t)c*TR*TC);
        float4 w = *(const float4*)(wb + c*OUP);
        acc[0][0] += z.x*w.x; acc[0][1] += z.x*w.y; acc[0][2] += z.x*w.z; acc[0][3] += z.x*w.w;
        acc[1][0] += z.y*w.x; acc[1][1] += z.y*w.y; acc[1][2] += z.y*w.z; acc[1][3] += z.y*w.w;
        acc[2][0] += z.z*w.x; acc[2][1] += z.z*w.y; acc[2][2] += z.z*w.z; acc[2][3] += z.z*w.w;
        acc[3][0] += z.w*w.x; acc[3][1] += z.w*w.y; acc[3][2] += z.w*w.z; acc[3][3] += z.w*w.w;
    }

    const float4 tt = *(const float4*)(t3 + oc*4);
    float* ob = out + (size_t)b*OUP*TR*TC + sp;
    #pragma unroll
    for (int o = 0; o < 4; ++o) {
        float tb = (o==0)?tt.x:(o==1)?tt.y:(o==2)?tt.z:tt.w;
        float4 r = make_float4(acc[0][o]+tb, acc[1][o]+tb, acc[2][o]+tb, acc[3][o]+tb);
        *(float4*)(ob + (size_t)(oc*4 + o)*TR*TC) = r;
    }
}

// ---------------------------------------------------------------------------
extern "C" void kernel_launch(void* const* d_in, const int* in_sizes, int n_in,
                              void* d_out, int out_size, void* d_ws, size_t ws_size,
                              hipStream_t stream)
{
    const float* x    = (const float*)d_in[0];
    const float* w1   = (const float*)d_in[1];
    const float* g1   = (const float*)d_in[2];
    const float* b1   = (const float*)d_in[3];
    const float* m1   = (const float*)d_in[4];
    const float* v1   = (const float*)d_in[5];
    const float* se_w = (const float*)d_in[6];
    const float* se_b = (const float*)d_in[7];
    const float* wdw  = (const float*)d_in[8];
    const float* g2   = (const float*)d_in[9];
    const float* b2   = (const float*)d_in[10];
    const float* m2   = (const float*)d_in[11];
    const float* v2   = (const float*)d_in[12];
    const float* w2   = (const float*)d_in[13];
    const float* g3   = (const float*)d_in[14];
    const float* b3   = (const float*)d_in[15];
    const float* m3   = (const float*)d_in[16];
    const float* v3   = (const float*)d_in[17];
    float* out = (float*)d_out;

    float* ws = (float*)d_ws;
    unsigned short* y = (unsigned short*)ws;   // 28,311,552 bf16 = 14,155,776 f
    float* z1      = ws + 14155776;            //  7,077,888
    float* se6     = ws + 21233664;            //        576
    int*   iW      = (int*)(ws + 21234240);    //     73,728
    float* AW      = ws + 21307968;            //     73,728
    float* BW      = ws + 21381696;            //     73,728
    float* mm      = ws + 21455424;            //     73,728
    int*   i2T     = (int*)(ws + 21529152);    //     36,864
    float* A2T     = ws + 21566016;            //     36,864
    float* B2T     = ws + 21602880;            //     36,864
    float* se_part = ws + 21639744;            //        576
    unsigned short* w1b = (unsigned short*)(ws + 21642048); // 6,144 bf16
    float* t1      = ws + 21648192;            //        192
    float* w2t     = ws + 21648384;            //     12,288
    float* t3      = ws + 21660672;            //         64

    k0_prep<<<76, 256, 0, stream>>>(w1, g1, b1, m1, v1, w2, g3, b3, m3, v3,
                                    w1b, t1, w2t, t3, se_part);
    k1_mfma<<<B_*144, 256, 0, stream>>>(x, w1b, t1, se_w, y, se_part);
    k2_se<<<3, 256, 0, stream>>>(se_part, se_b, se6);
    k3_rows<<<B_*H_, 128, 0, stream>>>(se6, iW, AW, BW, mm);
    k5_cols<<<B_*TC, 128, 0, stream>>>(mm, i2T, A2T, B2T);
    k4_warp_dw<<<B_*HID, 256, 0, stream>>>(y, iW, AW, BW, i2T, A2T, B2T,
                                           wdw, g2, b2, m2, v2, z1);
    k8_conv2<<<(B_*TR*TC)/64, 256, 0, stream>>>(z1, w2t, t3, out);
}

// Round 10
// 190.605 us; speedup vs baseline: 1.2764x; 1.1304x over previous
//
#include <hip/hip_runtime.h>
#include <hip/hip_bf16.h>
#include <math.h>

#define B_   16
#define INP  32
#define OUP  64
#define HID  192
#define H_   96
#define W_   96
#define HW_  (H_*W_)   // 9216
#define TC   48
#define TR   48

typedef __attribute__((ext_vector_type(8))) short  bf16x8;
typedef __attribute__((ext_vector_type(4))) float  f32x4;

__device__ __forceinline__ float relu6f(float v) { return fminf(fmaxf(v, 0.f), 6.f); }
__device__ __forceinline__ float bf2f(unsigned short u) {
    unsigned int x = ((unsigned int)u) << 16;
    return __uint_as_float(x);
}
__device__ __forceinline__ unsigned short f2bf(float f) {
    unsigned int x = __float_as_uint(f);
    unsigned int lsb = (x >> 16) & 1u;
    x += 0x7fffu + lsb;
    return (unsigned short)(x >> 16);
}

// ---------------------------------------------------------------------------
// K0: prep — BN1-folded bf16 w1b + t1; BN3-folded w2t + t3; BN2 -> sc2/sh2;
// zero se_part.
// ---------------------------------------------------------------------------
__global__ __launch_bounds__(256) void k0_prep(
    const float* __restrict__ w1, const float* __restrict__ g1,
    const float* __restrict__ b1, const float* __restrict__ m1,
    const float* __restrict__ v1,
    const float* __restrict__ w2, const float* __restrict__ g3,
    const float* __restrict__ b3, const float* __restrict__ m3,
    const float* __restrict__ v3,
    const float* __restrict__ g2, const float* __restrict__ b2,
    const float* __restrict__ m2, const float* __restrict__ v2,
    unsigned short* __restrict__ w1b, float* __restrict__ t1,
    float* __restrict__ w2t, float* __restrict__ t3,
    float* __restrict__ se_part, float* __restrict__ sc2,
    float* __restrict__ sh2)
{
    const int idx = blockIdx.x*256 + threadIdx.x;
    if (idx < HID*INP) {                                    // w1b (bf16)
        int o = idx / INP;
        w1b[idx] = f2bf(w1[idx] * g1[o]*rsqrtf(v1[o] + 1e-5f));
    } else if (idx < HID*INP + HID) {                       // t1
        int o = idx - HID*INP;
        float sc = g1[o]*rsqrtf(v1[o] + 1e-5f);
        t1[o] = b1[o] - m1[o]*sc;
    } else if (idx < HID*INP + HID + HID*OUP) {             // w2t
        int k = idx - (HID*INP + HID);
        int c = k / OUP, o = k % OUP;
        w2t[k] = w2[o*HID + c] * g3[o]*rsqrtf(v3[o] + 1e-5f);
    } else if (idx < HID*INP + HID + HID*OUP + OUP) {       // t3
        int o = idx - (HID*INP + HID + HID*OUP);
        float sc = g3[o]*rsqrtf(v3[o] + 1e-5f);
        t3[o] = b3[o] - m3[o]*sc;
    } else if (idx < HID*INP + HID + HID*OUP + OUP + B_*36) { // zero se_part
        se_part[idx - (HID*INP + HID + HID*OUP + OUP)] = 0.f;
    } else if (idx < HID*INP + HID + HID*OUP + OUP + B_*36 + HID) { // sc2
        int c = idx - (HID*INP + HID + HID*OUP + OUP + B_*36);
        sc2[c] = g2[c]*rsqrtf(v2[c] + 1e-5f);
    } else if (idx < HID*INP + HID + HID*OUP + OUP + B_*36 + 2*HID) { // sh2
        int c = idx - (HID*INP + HID + HID*OUP + OUP + B_*36 + HID);
        float sc = g2[c]*rsqrtf(v2[c] + 1e-5f);
        sh2[c] = b2[c] - m2[c]*sc;
    }
}

// ---------------------------------------------------------------------------
// K1 (MFMA): 1x1 conv (32->192) + BN1 + ReLU6 -> y (bf16); SE-weighted pool.
// ---------------------------------------------------------------------------
__global__ __launch_bounds__(256) void k1_mfma(
    const float* __restrict__ x, const unsigned short* __restrict__ w1b,
    const float* __restrict__ t1, const float* __restrict__ se_w,
    unsigned short* __restrict__ y, float* __restrict__ se_part)
{
    __shared__ unsigned short wl[HID*INP];   // 12 KiB  [oc][k] bf16
    __shared__ unsigned short xT[64*INP];    //  4 KiB  [px][k] bf16
    __shared__ float t1l[HID], sewl[HID];
    const int tid = threadIdx.x;
    const int bid = blockIdx.x;              // b*144 + strip64
    const int b   = bid / 144;
    const int inpx0 = (bid % 144) * 64;

    {
        const uint4* src = (const uint4*)w1b;
        uint4* dst = (uint4*)wl;
        dst[tid] = src[tid];
        if (tid < 256) { dst[tid+256] = src[tid+256]; dst[tid+512] = src[tid+512]; }
    }
    if (tid < HID) { t1l[tid] = t1[tid]; sewl[tid] = se_w[tid]; }
    {
        const int ch = tid >> 3, q8 = tid & 7;
        const float* xp = x + (size_t)(b*INP + ch)*HW_ + inpx0 + q8*8;
        float4 v0 = *(const float4*)(xp);
        float4 v1 = *(const float4*)(xp + 4);
        int p0 = q8*8;
        xT[(p0+0)*INP + ch] = f2bf(v0.x);
        xT[(p0+1)*INP + ch] = f2bf(v0.y);
        xT[(p0+2)*INP + ch] = f2bf(v0.z);
        xT[(p0+3)*INP + ch] = f2bf(v0.w);
        xT[(p0+4)*INP + ch] = f2bf(v1.x);
        xT[(p0+5)*INP + ch] = f2bf(v1.y);
        xT[(p0+6)*INP + ch] = f2bf(v1.z);
        xT[(p0+7)*INP + ch] = f2bf(v1.w);
    }
    __syncthreads();

    const int w = tid >> 6;
    const int l = tid & 63;
    const int pxl = l & 15;
    const int kb  = l >> 4;

    const bf16x8 bfrag = *(const bf16x8*)&xT[(w*16 + pxl)*INP + kb*8];
    const size_t ybase = (size_t)b*HID*HW_ + inpx0 + w*16 + pxl;
    float psum = 0.f;

    #pragma unroll
    for (int T = 0; T < 12; ++T) {
        const bf16x8 afrag = *(const bf16x8*)&wl[(T*16 + pxl)*INP + kb*8];
        f32x4 acc = __builtin_amdgcn_mfma_f32_16x16x32_bf16(
                        afrag, bfrag, (f32x4){0.f,0.f,0.f,0.f}, 0, 0, 0);
        const int oc0 = T*16 + kb*4;
        const float4 t1v = *(const float4*)&t1l[oc0];
        const float4 swv = *(const float4*)&sewl[oc0];
        float yv0 = relu6f(acc[0] + t1v.x);
        float yv1 = relu6f(acc[1] + t1v.y);
        float yv2 = relu6f(acc[2] + t1v.z);
        float yv3 = relu6f(acc[3] + t1v.w);
        psum += swv.x*yv0 + swv.y*yv1 + swv.z*yv2 + swv.w*yv3;
        y[ybase + (size_t)(oc0+0)*HW_] = f2bf(yv0);
        y[ybase + (size_t)(oc0+1)*HW_] = f2bf(yv1);
        y[ybase + (size_t)(oc0+2)*HW_] = f2bf(yv2);
        y[ybase + (size_t)(oc0+3)*HW_] = f2bf(yv3);
    }

    #pragma unroll
    for (int off = 32; off > 0; off >>= 1) psum += __shfl_down(psum, off, 64);
    if (l == 0) {
        const int spx = inpx0 + w*16;
        const int h = spx / W_, w0 = spx % W_;
        const int cell = (h >> 4)*6 + (w0 >> 4);
        atomicAdd(&se_part[b*36 + cell], psum);
    }
}

// ---------------------------------------------------------------------------
// K2: se6[b,cell] = sigmoid(pooled/256 + se_b)
// ---------------------------------------------------------------------------
__global__ __launch_bounds__(256) void k2_se(
    const float* __restrict__ se_part, const float* __restrict__ se_b,
    float* __restrict__ se6)
{
    const int id = blockIdx.x*256 + threadIdx.x;
    if (id < B_*36) {
        float logit = se_part[id]*(1.f/256.f) + se_b[0];
        se6[id] = 1.f/(1.f + expf(-logit));
    }
}

// ---------------------------------------------------------------------------
// K3: per (b,h) row — SE upsample, cumsum, searchsorted -> iABW={i,A,B,_}, mm
// ---------------------------------------------------------------------------
__global__ __launch_bounds__(128) void k3_rows(
    const float* __restrict__ se6,
    float4* __restrict__ iABW, float* __restrict__ mm)
{
    const int bx = blockIdx.x;            // b*H_ + h
    const int b = bx / H_, h = bx % H_;
    const int tid = threadIdx.x;
    __shared__ float ysr[W_];
    __shared__ float xxl[W_];

    const float* s6 = se6 + b*36;
    float ch = h * (5.0f/95.0f);
    int r0 = (int)floorf(ch); r0 = min(max(r0, 0), 4);
    float fr = ch - (float)r0;

    if (tid < W_) {
        float cw = tid * (5.0f/95.0f);
        int c0 = (int)floorf(cw); c0 = min(max(c0, 0), 4);
        float fc = cw - (float)c0;
        float v00 = s6[r0*6 + c0],     v01 = s6[r0*6 + c0 + 1];
        float v10 = s6[(r0+1)*6 + c0], v11 = s6[(r0+1)*6 + c0 + 1];
        float ra = v00*(1.f-fr) + v10*fr;
        float rb = v01*(1.f-fr) + v11*fr;
        ysr[tid] = ra*(1.f-fc) + rb*fc;
    }
    __syncthreads();
    if (tid == 0) {
        float rs = 0.f;
        for (int w = 0; w < W_; ++w) rs += ysr[w] + 0.001f;
        float scale = (W_*0.5f)/rs;
        float cum = 0.f;
        for (int w = 0; w < W_; ++w) { cum += scale*(ysr[w]+0.001f) + 0.5f; xxl[w] = cum; }
    }
    __syncthreads();
    if (tid < TC) {
        float cq = tid * 2.0f;
        int cnt = 0;
        for (int w = 0; w < W_; ++w) cnt += (xxl[w] < cq) ? 1 : 0;
        int i = min(max(cnt - 1, 0), W_ - 2);
        float x0 = xxl[i], x1 = xxl[i+1];
        float t = (cq - x0)/(x1 - x0);
        int idx = bx*TC + tid;
        float s0 = ysr[i], s1v = ysr[i+1];
        iABW[idx] = make_float4((float)i, s0*(1.f - t), s1v*t, 0.f);
        mm[idx] = s0 + (s1v - s0)*t;
    }
}

// ---------------------------------------------------------------------------
// K5: per (b,j) column — cumsum over h, searchsorted -> i2AB={i2,A2,B2,_}[b][r][j]
// ---------------------------------------------------------------------------
__global__ __launch_bounds__(128) void k5_cols(
    const float* __restrict__ mm, float4* __restrict__ i2AB)
{
    const int bx = blockIdx.x;            // b*TC + j
    const int b = bx / TC, j = bx % TC;
    const int tid = threadIdx.x;
    __shared__ float cmv[H_], yyl[H_];

    if (tid < H_) cmv[tid] = mm[(b*H_ + tid)*TC + j] + 0.001f;
    __syncthreads();
    if (tid == 0) {
        float cs = 0.f;
        for (int hh = 0; hh < H_; ++hh) cs += cmv[hh];
        float scale = (H_*0.5f)/cs;
        float cum = 0.f;
        for (int hh = 0; hh < H_; ++hh) { cum += scale*cmv[hh] + 0.5f; yyl[hh] = cum; }
    }
    __syncthreads();
    if (tid < TR) {
        float rq = tid * 2.0f;
        int cnt = 0;
        for (int hh = 0; hh < H_; ++hh) cnt += (yyl[hh] < rq) ? 1 : 0;
        int i2 = min(max(cnt - 1, 0), H_ - 2);
        float p0 = yyl[i2], p1 = yyl[i2+1];
        float t2 = (rq - p0)/(p1 - p0);
        int idx = (b*TR + tid)*TC + j;
        i2AB[idx] = make_float4((float)i2, 1.f - t2, t2, 0.f);
    }
}

// ---------------------------------------------------------------------------
// K4: FUSED horizontal warp + vertical warp + depthwise 3x3 + BN2 + ReLU6.
// block = one (b,c) plane. NO y staging (L1/L2 serves row gathers); only
// mf (18K) + ff (9K) in LDS -> 5 blocks/CU (was 3).
// ---------------------------------------------------------------------------
__global__ __launch_bounds__(256) void k4_warp_dw(
    const unsigned short* __restrict__ y,
    const float4* __restrict__ iABW,
    const float4* __restrict__ i2AB,
    const float* __restrict__ wdw,
    const float* __restrict__ sc2, const float* __restrict__ sh2,
    float* __restrict__ z1)
{
    __shared__ float mfs[H_*TC];         // 18 KiB
    __shared__ float ffs[TR*TC];         //  9 KiB
    const int tid = threadIdx.x;
    const int b = blockIdx.x / HID;
    const int c = blockIdx.x % HID;
    const unsigned short* yp = y + (size_t)(b*HID + c)*HW_;

    // Phase A: horizontal warp (SE gate folded into A/B), y gathered from L1/L2
    const int rbase = b*H_*TC;
    #pragma unroll
    for (int t = 0; t < (H_*TC)/256; ++t) {
        int k = tid + t*256;
        int h = k / TC;
        float4 f = iABW[rbase + k];
        int i = (int)f.x;
        float y0 = bf2f(yp[h*W_ + i]);
        float y1 = bf2f(yp[h*W_ + i + 1]);
        mfs[k] = y0*f.y + y1*f.z;
    }
    __syncthreads();

    // Phase B: vertical warp
    const int r2base = b*TR*TC;
    #pragma unroll
    for (int t = 0; t < (TR*TC)/256; ++t) {
        int k = tid + t*256;
        int j = k % TC;
        float4 f = i2AB[r2base + k];
        int i2 = (int)f.x;
        ffs[k] = mfs[i2*TC + j]*f.y + mfs[(i2+1)*TC + j]*f.z;
    }

    float wk[9];
    #pragma unroll
    for (int k = 0; k < 9; ++k) wk[k] = wdw[c*9 + k];
    const float sc = sc2[c], sh = sh2[c];
    __syncthreads();

    // Phase C: depthwise 3x3 SAME + BN2 + ReLU6
    float* zp = z1 + (size_t)(b*HID + c)*TR*TC;
    #pragma unroll
    for (int t = 0; t < (TR*TC)/256; ++t) {
        int k = tid + t*256;
        int r = k / TC, j = k % TC;
        float acc = 0.f;
        #pragma unroll
        for (int dr = -1; dr <= 1; ++dr)
            #pragma unroll
            for (int dj = -1; dj <= 1; ++dj) {
                int rr = r + dr, jj = j + dj;
                if (rr >= 0 && rr < TR && jj >= 0 && jj < TC)
                    acc += ffs[rr*TC + jj]*wk[(dr+1)*3 + (dj+1)];
            }
        zp[k] = relu6f(acc*sc + sh);
    }
}

// ---------------------------------------------------------------------------
// K8: 1x1 conv (192->64) + BN3 -> out. Register-tiled:
// thread = 4 px (float4) x 4 outputs; block = 16 pxg (64 px) x 16 o-chunks.
// ---------------------------------------------------------------------------
__global__ __launch_bounds__(256) void k8_conv2(
    const float* __restrict__ z1, const float* __restrict__ w2t,
    const float* __restrict__ t3, float* __restrict__ out)
{
    const int tid = threadIdx.x;
    const int pxg = tid & 15;
    const int oc  = tid >> 4;
    const int pix0 = blockIdx.x*64 + pxg*4;
    const int b   = pix0 / (TR*TC);
    const int sp  = pix0 % (TR*TC);

    float acc[4][4];
    #pragma unroll
    for (int p = 0; p < 4; ++p)
        #pragma unroll
        for (int o = 0; o < 4; ++o) acc[p][o] = 0.f;

    const float* zb = z1 + (size_t)b*HID*TR*TC + sp;
    const float* wb = w2t + oc*4;
    #pragma unroll 4
    for (int c = 0; c < HID; ++c) {
        float4 z = *(const float4*)(zb + (size_t)c*TR*TC);
        float4 w = *(const float4*)(wb + c*OUP);
        acc[0][0] += z.x*w.x; acc[0][1] += z.x*w.y; acc[0][2] += z.x*w.z; acc[0][3] += z.x*w.w;
        acc[1][0] += z.y*w.x; acc[1][1] += z.y*w.y; acc[1][2] += z.y*w.z; acc[1][3] += z.y*w.w;
        acc[2][0] += z.z*w.x; acc[2][1] += z.z*w.y; acc[2][2] += z.z*w.z; acc[2][3] += z.z*w.w;
        acc[3][0] += z.w*w.x; acc[3][1] += z.w*w.y; acc[3][2] += z.w*w.z; acc[3][3] += z.w*w.w;
    }

    const float4 tt = *(const float4*)(t3 + oc*4);
    float* ob = out + (size_t)b*OUP*TR*TC + sp;
    #pragma unroll
    for (int o = 0; o < 4; ++o) {
        float tb = (o==0)?tt.x:(o==1)?tt.y:(o==2)?tt.z:tt.w;
        float4 r = make_float4(acc[0][o]+tb, acc[1][o]+tb, acc[2][o]+tb, acc[3][o]+tb);
        *(float4*)(ob + (size_t)(oc*4 + o)*TR*TC) = r;
    }
}

// ---------------------------------------------------------------------------
extern "C" void kernel_launch(void* const* d_in, const int* in_sizes, int n_in,
                              void* d_out, int out_size, void* d_ws, size_t ws_size,
                              hipStream_t stream)
{
    const float* x    = (const float*)d_in[0];
    const float* w1   = (const float*)d_in[1];
    const float* g1   = (const float*)d_in[2];
    const float* b1   = (const float*)d_in[3];
    const float* m1   = (const float*)d_in[4];
    const float* v1   = (const float*)d_in[5];
    const float* se_w = (const float*)d_in[6];
    const float* se_b = (const float*)d_in[7];
    const float* wdw  = (const float*)d_in[8];
    const float* g2   = (const float*)d_in[9];
    const float* b2   = (const float*)d_in[10];
    const float* m2   = (const float*)d_in[11];
    const float* v2   = (const float*)d_in[12];
    const float* w2   = (const float*)d_in[13];
    const float* g3   = (const float*)d_in[14];
    const float* b3   = (const float*)d_in[15];
    const float* m3   = (const float*)d_in[16];
    const float* v3   = (const float*)d_in[17];
    float* out = (float*)d_out;

    float* ws = (float*)d_ws;
    unsigned short* y = (unsigned short*)ws;     // 28,311,552 bf16
    float*  z1     = ws + 14155776;              //  7,077,888
    float*  se6    = ws + 21233664;              //        576
    float4* iABW   = (float4*)(ws + 21234240);   //     73,728 float4
    float*  mm     = ws + 21529152;              //     73,728
    float4* i2AB   = (float4*)(ws + 21602880);   //     36,864 float4
    float*  se_part= ws + 21750336;              //        576
    unsigned short* w1b = (unsigned short*)(ws + 21750912); // 6,144 bf16
    float*  t1     = ws + 21753984;              //        192
    float*  w2t    = ws + 21754176;              //     12,288
    float*  t3     = ws + 21766464;              //         64
    float*  sc2    = ws + 21766528;              //        192
    float*  sh2    = ws + 21766720;              //        192

    k0_prep<<<77, 256, 0, stream>>>(w1, g1, b1, m1, v1, w2, g3, b3, m3, v3,
                                    g2, b2, m2, v2,
                                    w1b, t1, w2t, t3, se_part, sc2, sh2);
    k1_mfma<<<B_*144, 256, 0, stream>>>(x, w1b, t1, se_w, y, se_part);
    k2_se<<<3, 256, 0, stream>>>(se_part, se_b, se6);
    k3_rows<<<B_*H_, 128, 0, stream>>>(se6, iABW, mm);
    k5_cols<<<B_*TC, 128, 0, stream>>>(mm, i2AB);
    k4_warp_dw<<<B_*HID, 256, 0, stream>>>(y, iABW, i2AB, wdw, sc2, sh2, z1);
    k8_conv2<<<(B_*TR*TC)/64, 256, 0, stream>>>(z1, w2t, t3, out);
}